// Round 2
// baseline (20.586 us; speedup 1.0000x reference)
//
#include <hip/hip_runtime.h>
#include <math.h>

#define TPB 1024
#define KSEL 8
#define MAXCHUNK 14   // covers N4 <= 14*1024 = 14336 (N=56564 -> N4=14141)

// Monotone u64 key: unsigned order == (larger float wins; tie -> smaller index wins),
// matching jnp.argmax's first-index tie rule.
__device__ __forceinline__ unsigned long long make_key(float v, unsigned int idx) {
    unsigned int u = __float_as_uint(v);
    unsigned int ord = u ^ ((unsigned int)((int)u >> 31) | 0x80000000u);
    return ((unsigned long long)ord << 32) | (unsigned long long)(~idx);
}

__global__ __launch_bounds__(TPB, 1) void fused_topk_linear(
        const float* __restrict__ x, const float* __restrict__ pw,
        const float* __restrict__ w, const float* __restrict__ bias,
        float* __restrict__ out, int N, int H, int B) {
    __shared__ unsigned long long s_wavekeys[(TPB / 64) * KSEL];
    __shared__ int s_idx[KSEL];
    __shared__ float s_x[16][KSEL];

    const int tid  = threadIdx.x;
    const int lane = tid & 63;
    const int wid  = tid >> 6;
    const int N4   = N >> 2;
    const int tail = N - (N4 << 2);
    const float4* __restrict__ pw4 = reinterpret_cast<const float4*>(pw);

    // ---------------- Phase A: batched load + per-lane top-2 -------------
    // Load all chunks up-front (independent loads -> single latency exposure).
    float4 buf[MAXCHUNK];
    #pragma unroll
    for (int j = 0; j < MAXCHUNK; ++j) {
        int p = tid + j * TPB;
        int pp = (p < N4) ? p : 0;
        buf[j] = pw4[pp];
    }

    float m1 = -INFINITY, m2 = -INFINITY;
    unsigned int i1 = 0u, i2 = 0u;
    #pragma unroll
    for (int j = 0; j < MAXCHUNK; ++j) {
        int p = tid + j * TPB;
        bool valid = (p < N4);
        float f[4] = {buf[j].x, buf[j].y, buf[j].z, buf[j].w};
        unsigned int base = (unsigned int)p * 4u;
        #pragma unroll
        for (int c = 0; c < 4; ++c) {
            float v = valid ? f[c] : -INFINITY;
            unsigned int gi = base + (unsigned int)c;
            bool gt = (v > m1);
            float        lv = gt ? m1 : v;
            unsigned int li = gt ? i1 : gi;
            m1 = gt ? v  : m1;
            i1 = gt ? gi : i1;
            bool gt2 = (lv > m2);
            m2 = gt2 ? lv : m2;
            i2 = gt2 ? li : i2;
        }
    }
    // generic overflow chunks (zero iterations for this shape)
    for (int p = tid + MAXCHUNK * TPB; p < N4; p += TPB) {
        float4 v4 = pw4[p];
        float f[4] = {v4.x, v4.y, v4.z, v4.w};
        unsigned int base = (unsigned int)p * 4u;
        #pragma unroll
        for (int c = 0; c < 4; ++c) {
            float v = f[c]; unsigned int gi = base + (unsigned int)c;
            bool gt = (v > m1);
            float lv = gt ? m1 : v; unsigned int li = gt ? i1 : gi;
            m1 = gt ? v : m1; i1 = gt ? gi : i1;
            bool gt2 = (lv > m2);
            m2 = gt2 ? lv : m2; i2 = gt2 ? li : i2;
        }
    }
    // scalar tail (N % 4)
    if (tid < tail) {
        unsigned int gi = (unsigned int)(N4 * 4 + tid);
        float v = pw[gi];
        bool gt = (v > m1);
        float lv = gt ? m1 : v; unsigned int li = gt ? i1 : gi;
        m1 = gt ? v : m1; i1 = gt ? gi : i1;
        bool gt2 = (lv > m2);
        m2 = gt2 ? lv : m2; i2 = gt2 ? li : i2;
    }

    unsigned long long k1 = (m1 == -INFINITY) ? 0ull : make_key(m1, i1);
    unsigned long long k2 = (m2 == -INFINITY) ? 0ull : make_key(m2, i2);

    // ---------------- Phase B: per-wave top-8 (shfl-only, no barriers) ----
    #pragma unroll 1
    for (int p = 0; p < KSEL; ++p) {
        unsigned long long wmax = k1;
        #pragma unroll
        for (int o = 32; o > 0; o >>= 1) {
            unsigned long long other = __shfl_xor(wmax, o, 64);
            if (other > wmax) wmax = other;
        }
        if (lane == 0) s_wavekeys[wid * KSEL + p] = wmax;
        if (k1 == wmax && wmax != 0ull) {
            unsigned long long nk = k2;
            if (nk == 0ull) {
                // rare: rescan my elements for max key strictly below wmax (L2-hot)
                for (int q = tid; q < N4; q += TPB) {
                    float4 v4 = pw4[q];
                    float f[4] = {v4.x, v4.y, v4.z, v4.w};
                    unsigned int base = (unsigned int)q * 4u;
                    #pragma unroll
                    for (int c = 0; c < 4; ++c) {
                        unsigned long long k = make_key(f[c], base + (unsigned int)c);
                        if (k < wmax && k > nk) nk = k;
                    }
                }
                if (tid < tail) {
                    unsigned int gi = (unsigned int)(N4 * 4 + tid);
                    unsigned long long k = make_key(pw[gi], gi);
                    if (k < wmax && k > nk) nk = k;
                }
            }
            k1 = nk;
            k2 = 0ull;
        }
    }
    __syncthreads();

    // ---------------- Phase C: one wave merges 128 candidates -------------
    if (wid == 0) {
        unsigned long long c0 = s_wavekeys[lane * 2];
        unsigned long long c1 = s_wavekeys[lane * 2 + 1];
        #pragma unroll 1
        for (int p = 0; p < KSEL; ++p) {
            unsigned long long m = (c0 > c1) ? c0 : c1;
            #pragma unroll
            for (int o = 32; o > 0; o >>= 1) {
                unsigned long long other = __shfl_xor(m, o, 64);
                if (other > m) m = other;
            }
            if (lane == 0) s_idx[p] = (int)(~(unsigned int)(m & 0xffffffffull));
            if (c0 == m) c0 = 0ull;
            if (c1 == m) c1 = 0ull;
        }
    }
    __syncthreads();

    // ---------------- Phase D: gather + tiny matmul -----------------------
    if (tid < B * KSEL) {
        int b = tid >> 3, k = tid & 7;
        s_x[b][k] = x[(size_t)b * N + s_idx[k]];
    }
    __syncthreads();

    int groups = TPB / H;                   // 4 for H=256
    if (groups < 1) groups = 1;
    int h = tid % H;
    int g = tid / H;
    if (g < groups && h < H) {
        int bpg = (B + groups - 1) / groups; // 2 for B=8
        float wv[KSEL];
        #pragma unroll
        for (int k = 0; k < KSEL; ++k) wv[k] = w[(size_t)s_idx[k] * H + h];
        float bv = bias[h];
        for (int bb = 0; bb < bpg; ++bb) {
            int b = g * bpg + bb;
            if (b < B) {
                float acc = bv;
                #pragma unroll
                for (int k = 0; k < KSEL; ++k) acc += s_x[b][k] * wv[k];
                out[(size_t)b * H + h] = acc;
            }
        }
    }
}

extern "C" void kernel_launch(void* const* d_in, const int* in_sizes, int n_in,
                              void* d_out, int out_size, void* d_ws, size_t ws_size,
                              hipStream_t stream) {
    const float* x    = (const float*)d_in[0];
    const float* pw   = (const float*)d_in[1];
    const float* w    = (const float*)d_in[2];
    const float* bias = (const float*)d_in[3];
    float* out = (float*)d_out;

    const int N = in_sizes[1];        // 56564
    const int H = in_sizes[3];        // 256
    const int B = in_sizes[0] / N;    // 8

    fused_topk_linear<<<1, TPB, 0, stream>>>(x, pw, w, bias, out, N, H, B);
}